// Round 12
// baseline (101.076 us; speedup 1.0000x reference)
//
#include <hip/hip_runtime.h>

// StericClashConstraint: N=16384 pts [N,3] fp32.
// out[0..3N-1] = pos passthrough; out[3N] = mean(max(1-dist,0), diag=0) * 0.02
//
// Round 18: final retry of the 2-dispatch self-gather (R15), de-exoticized.
// R17 (3-dispatch, 78.9us) is the banked fallback. Budget: 40us fill poison +
// ~27us fixed floor + ~12us controllable; killing one dispatch gap + the
// scatter kernel's global jt4s round-trip is worth ~5-7us.
// R15/R16 container-failed twice with no auditable fault path; the one
// untested suspect was exotic codegen from `#pragma unroll 4/8` around
// conditional 2D-LDS stores -> ALL unroll pragmas removed here (plain loops).
// Design (R15, components individually proven in R13/R17):
//  k1 prep:  copy + per-block LDS z-hist -> histPart; pack (cell,rank) in crk
//            (rank = LDS-atomic return, the ONE nondeterministic-but-shared
//            ordering source -> globally consistent); pack p4 {x,y,z,|p|^2};
//            zero acc/cnt.
//  k2 fused: every block redundantly builds prefT[64][256] (ushort, 32KB LDS,
//            prefix of histPart over prep-rows -- free byproduct of the
//            reduction) + Hillis-Steele scan; computes its group's jend from
//            the in-LDS scan; gathers its OWN i-range and j-chunk into LDS via
//            gdst = excl[cell] + prefT[p][cell] + rank (R13-proven formula);
//            then the R13-verbatim pair body; acc/cnt finalize.
// Zero inter-block communication in k2 -> no barrier (R14 lesson: any
// single-address grid barrier costs ~35us on 8 non-coherent XCDs).
// MARGIN=5 proof (R17-verified): cell=floor(4z) exact in fp32; excluded j has
// dz > 1.0 strictly => max(1-dist,0) = 0 exactly. Pair math bit-identical R8+.

constexpr int   N     = 16384;
constexpr int   BLOCK = 256;            // 4 waves
constexpr int   GSZ   = 512;            // i-group size
constexpr int   IPT   = GSZ / BLOCK;    // 2 i's per thread
constexpr int   NG    = N / GSZ;        // 32 i-groups
constexpr int   F     = 8;              // j-segments per group
constexpr int   NB    = NG * F;         // 256 fused blocks = 1/CU
constexpr int   QB    = 4;              // columns per unrolled chunk
constexpr int   NBINS = 256;            // z-bins, width 1/4, covering [-32,32)
constexpr float BINW_INV = 4.0f;        // *4 exact in fp32
constexpr int   MARGIN = 5;             // cell_j >= cell_last+5 => dz > 1.0 strict
constexpr int   CH2   = 384;            // gathered j-columns per chunk (1 typ.)
constexpr int   NHB   = N / BLOCK;      // 64 prep blocks

__device__ __forceinline__ int zcell(float z) {
    int c = (int)floorf(z * BINW_INV) + NBINS / 2;
    return min(max(c, 0), NBINS - 1);
}

// ---- k1: passthrough + per-block partial hist + (cell,rank) + packed p4 ----
__global__ void __launch_bounds__(BLOCK)
prep_kernel(const float* __restrict__ pos, float* __restrict__ out,
            unsigned int* __restrict__ histPart, unsigned int* __restrict__ crk,
            float4* __restrict__ p4,
            float* __restrict__ acc, unsigned int* __restrict__ cnt) {
    __shared__ unsigned int lh[NBINS];
    const int b = blockIdx.x, t = threadIdx.x;
    const int gt = b * BLOCK + t;                     // 0..16383
    lh[t] = 0u;                                       // NBINS == BLOCK
    if (gt == 0) { *acc = 0.0f; *cnt = 0u; }          // replay-safe init
    __syncthreads();
    if (gt < (N * 3) / 4) {
        reinterpret_cast<float4*>(out)[gt] = reinterpret_cast<const float4*>(pos)[gt];
    }
    const float x = pos[3 * gt], y = pos[3 * gt + 1], z = pos[3 * gt + 2];
    p4[gt] = make_float4(x, y, z, fmaf(x, x, fmaf(y, y, z * z)));  // unsorted pack
    const int cell = zcell(z);
    const unsigned int rank = atomicAdd(&lh[cell], 1u);   // rank in (block,cell)
    crk[gt] = (unsigned int)cell | (rank << 16);
    __syncthreads();
    histPart[b * NBINS + t] = lh[t];
}

// ---- pair inner loop (R13 verbatim) ----------------------------------------
template <bool MASKED>
__device__ __forceinline__ float cols(const float4* __restrict__ jsm,
                                      int clen, int jbase, int i0,
                                      const float (&xi2)[IPT], const float (&yi2)[IPT],
                                      const float (&zi2)[IPT], const float (&sqi)[IPT]) {
    float s = 0.0f;
    for (int c = 0; c < clen; c += QB) {              // sentinel pad covers overrun
        #pragma unroll
        for (int u = 0; u < QB; ++u) {
            const float4 pj = jsm[c + u];             // uniform addr -> broadcast
            const int jq = jbase + c + u;
            #pragma unroll
            for (int k = 0; k < IPT; ++k) {
                float d = fmaf(xi2[k], pj.x, pj.w);
                d = fmaf(yi2[k], pj.y, d);
                d = fmaf(zi2[k], pj.z, d);                     // sq_j - 2*dot
                const float d2 = fmaxf(d + sqi[k], 0.0f);      // + sq_i, clamp
                float w = 1.0f - __builtin_amdgcn_sqrtf(d2);   // 1 - dist
                w = fmaxf(w, 0.0f);                            // clamp(min=0)
                if (MASKED) w = (jq > i0 + k * BLOCK) ? w : 0.0f;   // j>i only
                s += w;
            }
        }
    }
    return s;
}

// ---- k2: scan + self-gather (no inter-block deps) + pair -------------------
__global__ void __launch_bounds__(BLOCK)
fused_kernel(const unsigned int* __restrict__ histPart,
             const unsigned int* __restrict__ crk, const float4* __restrict__ p4,
             float* __restrict__ out, float* __restrict__ acc,
             unsigned int* __restrict__ cnt) {
    __shared__ unsigned short prefT[NHB][NBINS];      // 32 KB (values <= 16128)
    __shared__ int sm[NBINS];
    __shared__ float4 ism[GSZ];                       // 8 KB: my group's i-points
    __shared__ float4 jsm[CH2 + QB];                  // 6.2 KB: j-chunk
    __shared__ float wsum[BLOCK / 64];
    const int b = blockIdx.x, t = threadIdx.x;
    const int g = b >> 3, f = b & (F - 1);
    const int gstart = g * GSZ;

    // --- histogram reduction + prefix table (plain loop, no unroll pragma) ---
    int run = 0;
    for (int p = 0; p < NHB; ++p) {                   // coalesced L2/L3 reads
        prefT[p][t] = (unsigned short)run;            // prefix over rows < p
        run += (int)histPart[p * NBINS + t];
    }
    sm[t] = run;
    __syncthreads();
    for (int off = 1; off < NBINS; off <<= 1) {       // Hillis-Steele inclusive
        const int a = (t >= off) ? sm[t - off] : 0;
        __syncthreads();
        sm[t] += a;
        __syncthreads();
    }

    // --- my group's j-window end, from the in-LDS scan (uniform) ---
    int jend;
    {
        const int target = gstart + GSZ;              // last idx of group + 1
        int lo = 0, hi = NBINS - 1;
        while (lo < hi) {                             // smallest c: incl[c] >= target
            const int mid = (lo + hi) >> 1;
            if (sm[mid] >= target) hi = mid; else lo = mid + 1;
        }
        const int jidx = lo + MARGIN;
        jend = (jidx >= NBINS) ? N : sm[jidx - 1];    // excl[jidx]
    }
    const int jbeg = gstart + 1;
    const int jlen = jend - jbeg;                     // >= GSZ-1 always
    const int seg  = (((jlen + F - 1) / F) + QB - 1) & ~(QB - 1);  // QB-aligned
    const int j0   = jbeg + f * seg;
    const int len  = min(seg, jend - j0);             // > 0 for all f (jlen>=511)
    const int i0   = gstart + t;

    float s = 0.0f;
    float xi2[IPT] = {0.f, 0.f}, yi2[IPT] = {0.f, 0.f};
    float zi2[IPT] = {0.f, 0.f}, sqi[IPT] = {0.f, 0.f};

    for (int cs = 0; cs < len; cs += CH2) {           // 1 chunk for typical data
        const int j0c  = j0 + cs;
        const int clen = min(CH2, len - cs);
        // --- gather: route my needed sorted slots into ism / jsm ---
        for (int p = 0; p < NHB; ++p) {               // plain loop, no pragma
            const unsigned int cr = crk[p * BLOCK + t];       // coalesced
            const int cell = (int)(cr & 0xffffu);
            const int rank = (int)(cr >> 16);
            const int ex   = (cell > 0) ? sm[cell - 1] : 0;
            const int gdst = ex + (int)prefT[p][cell] + rank; // global sorted slot
            const unsigned int ui = (unsigned int)(gdst - gstart);
            const unsigned int uj = (unsigned int)(gdst - j0c);
            const bool ini = (cs == 0) && (ui < (unsigned int)GSZ);
            const bool inj = (uj < (unsigned int)clen);
            if (ini || inj) {
                const float4 v = p4[p * BLOCK + t];           // rare (~5% lanes)
                if (ini) ism[ui] = v;
                if (inj) jsm[uj] = v;
            }
        }
        if (t < QB) jsm[clen + t] = make_float4(0.0f, 0.0f, 1.0e6f, 4.0e12f);
        __syncthreads();
        if (cs == 0) {                                // i-fragments, once
            const float4 w0 = ism[t];
            const float4 w1 = ism[t + BLOCK];
            xi2[0] = -2.0f*w0.x; yi2[0] = -2.0f*w0.y; zi2[0] = -2.0f*w0.z; sqi[0] = w0.w;
            xi2[1] = -2.0f*w1.x; yi2[1] = -2.0f*w1.y; zi2[1] = -2.0f*w1.z; sqi[1] = w1.w;
        }
        if (j0c < gstart + GSZ)        // chunk overlaps own group: j>i mask
            s += cols<true >(jsm, clen, j0c, i0, xi2, yi2, zi2, sqi);
        else
            s += cols<false>(jsm, clen, j0c, i0, xi2, yi2, zi2, sqi);
        __syncthreads();               // before next chunk overwrites jsm
    }

    // reduce: wave shuffle -> LDS -> one atomic per block
    for (int off = 32; off > 0; off >>= 1) s += __shfl_down(s, off);
    if ((t & 63) == 0) wsum[t >> 6] = s;
    __syncthreads();
    if (t == 0) {
        float bs = 0.0f;
        #pragma unroll
        for (int w = 0; w < BLOCK / 64; ++w) bs += wsum[w];
        atomicAdd(acc, bs);
        __threadfence();
        const unsigned int done = atomicAdd(cnt, 1u);
        if (done == (unsigned int)(NB - 1)) {          // last block finalizes
            __threadfence();
            const float total = atomicAdd(acc, 0.0f);  // device-coherent read
            const double mean = 2.0 * (double)total / ((double)N * (double)N);
            out[(size_t)N * 3] = (float)(mean * 0.02);
        }
    }
}

extern "C" void kernel_launch(void* const* d_in, const int* in_sizes, int n_in,
                              void* d_out, int out_size, void* d_ws, size_t ws_size,
                              hipStream_t stream) {
    const float* pos = (const float*)d_in[0];
    float* out = (float*)d_out;
    // ws layout:
    //   0:      acc (float)   4: cnt (uint)
    //   4096:   histPart[64][256]    (64 KiB)   -> ends 69632
    //   69632:  crk[16384] (uint)    (64 KiB)   -> ends 135168
    //   135168: p4[N x float4]       (256 KiB, UNSORTED pack {x,y,z,|p|^2})
    float*        acc      = (float*)d_ws;
    unsigned int* cnt      = (unsigned int*)d_ws + 1;
    unsigned int* histPart = (unsigned int*)((char*)d_ws + 4096);
    unsigned int* crk      = (unsigned int*)((char*)d_ws + 69632);
    float4*       p4       = (float4*)((char*)d_ws + 135168);

    prep_kernel <<<NHB, BLOCK, 0, stream>>>(pos, out, histPart, crk, p4, acc, cnt);
    fused_kernel<<<NB,  BLOCK, 0, stream>>>(histPart, crk, p4, out, acc, cnt);
}

// Round 13
// 74.752 us; speedup vs baseline: 1.3522x; 1.3522x over previous
//
#include <hip/hip_runtime.h>

// StericClashConstraint: N=16384 pts [N,3] fp32.
// out[0..3N-1] = pos passthrough; out[3N] = mean(max(1-dist,0), diag=0) * 0.02
//
// Round 19: R17 structure (proven 78.9us) + pair at 2 waves/SIMD.
// R18 post-mortem: 2-dispatch self-gather REFUTED by measurement (48us, VALU
// 16%): redundant 64-row gather/scan per block at 1 wave/SIMD = fully exposed
// L2/cross-XCD latency x64 iterations, + 281k LDS bank conflicts from random
// prefT[p][cell] ushort reads. Scatter's single pass + kernel-boundary sync
// (R17) is strictly better. Kept: prep/scatter BYTE-IDENTICAL to R17.
// Change: pair_kernel 256 -> 512 threads (8 waves, IPT=1). Same total VALU
// work (per-pair math bit-identical since R8), but 2 waves/SIMD hides the
// LDS-staging latency and sqrt-chain bubbles that a lone wave eats at
// 1 blk/CU. 384-col chunk stages in ONE guarded round now. Per-thread
// summation regrouping only (absmax-neutral across R9/R11's bigger regroups).
//  k1 prep:    copy + per-block LDS z-hist -> partials; (cell,rank) in crk.
//  k2 scatter: 64 blocks redundantly reduce+scan partials; atomic-free
//              scatter dst = excl+beforeB+rank; block 0 writes jendArr.
//  k3 pair:    256 blocks x 512 thr, LDS-staged j-chunks, branchless math.
// MARGIN=5 (R17-proven): cell=floor(4z) exact; excluded dz > 1.0 strictly.

constexpr int   N     = 16384;
constexpr int   BLOCK = 256;            // prep/scatter block size
constexpr int   PBLK  = 512;            // pair block size (8 waves)
constexpr int   GSZ   = 512;            // i-group size
constexpr int   IPT   = 1;              // i's per pair thread (PBLK == GSZ)
constexpr int   NG    = N / GSZ;        // 32 i-groups
constexpr int   F     = 8;              // j-segments per group
constexpr int   NB    = NG * F;         // 256 pair blocks = 1/CU
constexpr int   QB    = 4;              // columns per unrolled chunk
constexpr int   NBINS = 256;            // z-bins, width 1/4, covering [-32,32)
constexpr float BINW_INV = 4.0f;        // *4 exact in fp32
constexpr int   MARGIN = 5;             // cell_j >= cell_last+5 => dz > 1.0 strict
constexpr int   CH    = 384;            // columns staged per LDS chunk (1 round)
constexpr int   NHB   = N / BLOCK;      // 64 blocks own the points

__device__ __forceinline__ int zcell(float z) {
    int c = (int)floorf(z * BINW_INV) + NBINS / 2;
    return min(max(c, 0), NBINS - 1);
}

// ---- k1: passthrough + per-block partial hist + (cell,rank) pack -----------
__global__ void __launch_bounds__(BLOCK)
prep_kernel(const float* __restrict__ pos, float* __restrict__ out,
            unsigned int* __restrict__ histPart, unsigned int* __restrict__ crk,
            float* __restrict__ acc, unsigned int* __restrict__ cnt) {
    __shared__ unsigned int lh[NBINS];
    const int b = blockIdx.x, t = threadIdx.x;
    const int gt = b * BLOCK + t;                     // 0..16383
    lh[t] = 0u;                                       // NBINS == BLOCK
    if (gt == 0) { *acc = 0.0f; *cnt = 0u; }          // replaces memset dispatch
    __syncthreads();
    if (gt < (N * 3) / 4) {
        reinterpret_cast<float4*>(out)[gt] = reinterpret_cast<const float4*>(pos)[gt];
    }
    const float z = pos[3 * gt + 2];
    const int cell = zcell(z);
    const unsigned int rank = atomicAdd(&lh[cell], 1u);   // rank in (block,cell)
    crk[gt] = (unsigned int)cell | (rank << 16);
    __syncthreads();
    histPart[b * NBINS + t] = lh[t];
}

// ---- k2: redundant scan per block + atomic-free scatter + jendArr ----------
__global__ void __launch_bounds__(BLOCK)
scatter_kernel(const float* __restrict__ pos, const unsigned int* __restrict__ histPart,
               const unsigned int* __restrict__ crk, float4* __restrict__ jt4s,
               int* __restrict__ jendArr) {
    __shared__ int sm[NBINS];
    __shared__ int beforeB[NBINS];
    const int b = blockIdx.x, t = threadIdx.x;        // 64 blocks x 256
    int v = 0, bef = 0;
    #pragma unroll 8
    for (int p = 0; p < NHB; ++p) {                   // coalesced L2 reads
        const int hv = (int)histPart[p * NBINS + t];
        if (p == b) bef = v;                          // sum over blocks < b
        v += hv;
    }
    sm[t] = v; beforeB[t] = bef;
    __syncthreads();
    for (int off = 1; off < NBINS; off <<= 1) {       // Hillis-Steele inclusive
        const int a = (t >= off) ? sm[t - off] : 0;
        __syncthreads();
        sm[t] += a;
        __syncthreads();
    }
    // scatter own 256 points, no atomics
    const int gt = b * BLOCK + t;
    const unsigned int cr = crk[gt];
    const int cell = (int)(cr & 0xffffu);
    const int rank = (int)(cr >> 16);
    const int ex   = (cell > 0) ? sm[cell - 1] : 0;
    const int dst  = ex + beforeB[cell] + rank;
    const float x = pos[3 * gt], y = pos[3 * gt + 1], z = pos[3 * gt + 2];
    jt4s[dst] = make_float4(x, y, z, fmaf(x, x, fmaf(y, y, z * z)));
    // block 0: per-group j-window ends
    if (b == 0 && t < NG) {
        const int p = (t + 1) * GSZ - 1;              // last sorted idx of group
        int lo = 0, hi = NBINS - 1;
        while (lo < hi) {                             // smallest c: incl[c] >= p+1
            const int mid = (lo + hi) >> 1;
            if (sm[mid] >= p + 1) hi = mid; else lo = mid + 1;
        }
        const int jidx = lo + MARGIN;
        jendArr[t] = (jidx >= NBINS) ? N : sm[jidx - 1];   // excl[jidx]
    }
}

// ---- k3: pruned pair sweep, 8 waves/block ----------------------------------
template <bool MASKED>
__device__ __forceinline__ float cols(const float4* __restrict__ jsm,
                                      int clen, int jbase, int i0,
                                      float xi2, float yi2, float zi2, float sqi) {
    float s = 0.0f;
    for (int c = 0; c < clen; c += QB) {              // sentinel pad covers overrun
        #pragma unroll
        for (int u = 0; u < QB; ++u) {
            const float4 pj = jsm[c + u];             // uniform addr -> broadcast
            const int jq = jbase + c + u;
            float d = fmaf(xi2, pj.x, pj.w);
            d = fmaf(yi2, pj.y, d);
            d = fmaf(zi2, pj.z, d);                            // sq_j - 2*dot
            const float d2 = fmaxf(d + sqi, 0.0f);             // + sq_i, clamp
            float w = 1.0f - __builtin_amdgcn_sqrtf(d2);       // 1 - dist
            w = fmaxf(w, 0.0f);                                // clamp(min=0)
            if (MASKED) w = (jq > i0) ? w : 0.0f;              // j>i only
            s += w;
        }
    }
    return s;
}

__global__ void __launch_bounds__(PBLK)
pair_kernel(const float4* __restrict__ jt4s, const int* __restrict__ jendArr,
            float* __restrict__ out, float* __restrict__ acc,
            unsigned int* __restrict__ cnt) {
    __shared__ float4 jsm[CH + QB];
    __shared__ float wsum[PBLK / 64];
    const int b = blockIdx.x;
    const int t = threadIdx.x;
    const int g = b >> 3, f = b & (F - 1);
    const int gstart = g * GSZ;
    const int i0 = gstart + t;                         // one i per thread

    // issue i-point load first (overlap with jend load + param math)
    const float4 w0 = jt4s[i0];

    const int jend = jendArr[g];                       // one scalar load
    const int jbeg = gstart + 1;
    const int jlen = jend - jbeg;                      // >= GSZ-1 always
    const int seg  = (((jlen + F - 1) / F) + QB - 1) & ~(QB - 1);  // QB-aligned
    const int j0   = jbeg + f * seg;
    const int len  = min(seg, jend - j0);              // > 0 for all f (jlen>=511)

    const float xi2 = -2.0f * w0.x, yi2 = -2.0f * w0.y, zi2 = -2.0f * w0.z;
    const float sqi = w0.w;

    float s = 0.0f;
    for (int cs = 0; cs < len; cs += CH) {             // 1 chunk for typical data
        const int clen = min(CH, len - cs);
        if (t < clen) jsm[t] = jt4s[j0 + cs + t];      // one round: PBLK >= CH
        if (t < QB)   jsm[clen + t] = make_float4(0.0f, 0.0f, 1.0e6f, 4.0e12f);
        __syncthreads();
        if (j0 + cs < gstart + GSZ)    // chunk may overlap own group: j>i mask
            s += cols<true >(jsm, clen, j0 + cs, i0, xi2, yi2, zi2, sqi);
        else
            s += cols<false>(jsm, clen, j0 + cs, i0, xi2, yi2, zi2, sqi);
        __syncthreads();               // before next chunk overwrites jsm
    }

    // reduce: wave shuffle -> LDS -> one atomic per block
    for (int off = 32; off > 0; off >>= 1) s += __shfl_down(s, off);
    if ((t & 63) == 0) wsum[t >> 6] = s;
    __syncthreads();
    if (t == 0) {
        float bs = 0.0f;
        #pragma unroll
        for (int w = 0; w < PBLK / 64; ++w) bs += wsum[w];
        atomicAdd(acc, bs);
        __threadfence();
        const unsigned int done = atomicAdd(cnt, 1u);
        if (done == (unsigned int)(NB - 1)) {          // last block finalizes
            __threadfence();
            const float total = atomicAdd(acc, 0.0f);  // device-coherent read
            const double mean = 2.0 * (double)total / ((double)N * (double)N);
            out[(size_t)N * 3] = (float)(mean * 0.02);
        }
    }
}

extern "C" void kernel_launch(void* const* d_in, const int* in_sizes, int n_in,
                              void* d_out, int out_size, void* d_ws, size_t ws_size,
                              hipStream_t stream) {
    const float* pos = (const float*)d_in[0];
    float* out = (float*)d_out;
    // ws layout:
    //   0:      acc (float)      4: cnt (uint)
    //   256:    jendArr[32]          (128 B)
    //   4096:   histPart[64][256]    (64 KiB)   -> ends 69632
    //   69632:  crk[16384] (uint)    (64 KiB)   -> ends 135168
    //   135168: jt4s[N x float4]     (256 KiB)
    float*        acc      = (float*)d_ws;
    unsigned int* cnt      = (unsigned int*)d_ws + 1;
    int*          jendArr  = (int*)((char*)d_ws + 256);
    unsigned int* histPart = (unsigned int*)((char*)d_ws + 4096);
    unsigned int* crk      = (unsigned int*)((char*)d_ws + 69632);
    float4*       jt4s     = (float4*)((char*)d_ws + 135168);

    prep_kernel   <<<NHB, BLOCK, 0, stream>>>(pos, out, histPart, crk, acc, cnt);
    scatter_kernel<<<NHB, BLOCK, 0, stream>>>(pos, histPart, crk, jt4s, jendArr);
    pair_kernel   <<<NB,  PBLK,  0, stream>>>(jt4s, jendArr, out, acc, cnt);
}